// Round 19
// baseline (257.233 us; speedup 1.0000x reference)
//
// Round 19: gemm = r16 base (best 224.9us) with B read DIRECT from L2-resident
// theta^T into MFMA regs (no B staging/LDS): staging volume 24->8 KB/step,
// vmcnt(2) A-only, B-load latency hidden under MFMA+TLP. Memset folded into
// theta-transpose. Rest byte-identical to round-16.
#include <hip/hip_runtime.h>
#include <hip/hip_bf16.h>
#include <cstdint>
#include <cstddef>

#define N_NODES 10000
#define KNN_K 20
#define NEDGE (N_NODES * KNN_K)
#define NBATCH 157                 // ceil(10000/64)
#define POS4_PAD 10048             // 157*64
#define NCELL 4096                 // 16x16x16 spatial cells, h=0.5
#define NPX 1250                   // nodes per XCD chunk (10000/8)
#define GM_PAIRS 628               // 157 n-tiles (64) x 4 o-tiles (128)

using bf16x8 = __attribute__((ext_vector_type(8))) short;
using f32x4  = __attribute__((ext_vector_type(4))) float;

__device__ __forceinline__ float bf_lo(unsigned int u) {
  union { unsigned int i; float f; } c; c.i = u << 16; return c.f;
}
__device__ __forceinline__ float bf_hi(unsigned int u) {
  union { unsigned int i; float f; } c; c.i = u & 0xFFFF0000u; return c.f;
}
__device__ __forceinline__ unsigned short f2bf(float f) {
  union { float f; unsigned int i; } c; c.f = f;
  unsigned int u = c.i;
  u += 0x7FFFu + ((u >> 16) & 1u);   // RNE
  return (unsigned short)(u >> 16);
}

__device__ __forceinline__ void gll16(const void* g, void* l) {
  __builtin_amdgcn_global_load_lds(
      (const __attribute__((address_space(1))) unsigned int*)g,
      (__attribute__((address_space(3))) unsigned int*)l,
      16, 0, 0);
}

// ---------------- transpose f32 [srows][scols] -> bf16 dst[col][dcol0 + row] ----------------
// zbuf: if non-null, blocks (z==0,y==0,x<8) zero zbuf[0..8191] (cellcnt+cellcur)
__global__ __launch_bounds__(256) void transpose_f32_bf16(
    const float* __restrict__ src0, unsigned short* __restrict__ dst,
    int srows, int scols, int dstride, size_t slice_elems, int dcol_per_slice,
    int* __restrict__ zbuf)
{
  __shared__ float lds[64 * 65];
  const int z = blockIdx.z;
  if (zbuf != nullptr && z == 0 && blockIdx.y == 0 && blockIdx.x < 8) {
    int4 zz = make_int4(0, 0, 0, 0);
    *(int4*)&zbuf[(blockIdx.x * 256 + threadIdx.x) * 4] = zz;
  }
  const float* src = src0 + (size_t)z * slice_elems;
  const int dcol0 = z * dcol_per_slice;
  const int c0 = blockIdx.x * 64;
  const int r0 = blockIdx.y * 64;
  const int tid = threadIdx.x;
#pragma unroll
  for (int q = 0; q < 4; ++q) {
    int unit = q * 256 + tid;            // 1024 float4 units
    int rr = unit >> 4;                  // 0..63
    int cu = unit & 15;                  // 0..15
    int r = r0 + rr, c = c0 + cu * 4;
    float4 v = make_float4(0.f, 0.f, 0.f, 0.f);
    if (r < srows && c + 3 < scols) v = *(const float4*)&src[(size_t)r * scols + c];
    lds[rr * 65 + cu * 4 + 0] = v.x;
    lds[rr * 65 + cu * 4 + 1] = v.y;
    lds[rr * 65 + cu * 4 + 2] = v.z;
    lds[rr * 65 + cu * 4 + 3] = v.w;
  }
  __syncthreads();
#pragma unroll
  for (int q = 0; q < 2; ++q) {
    int unit = q * 256 + tid;            // 512 units of 8 bf16
    int cl = unit >> 3;                  // src col within tile (= dst row)
    int ru = unit & 7;
    int c = c0 + cl;
    if (c < scols) {
      unsigned short tmp[8];
#pragma unroll
      for (int j = 0; j < 8; ++j) tmp[j] = f2bf(lds[(ru * 8 + j) * 65 + cl]);
      uint4 o;
      o.x = (unsigned int)tmp[0] | ((unsigned int)tmp[1] << 16);
      o.y = (unsigned int)tmp[2] | ((unsigned int)tmp[3] << 16);
      o.z = (unsigned int)tmp[4] | ((unsigned int)tmp[5] << 16);
      o.w = (unsigned int)tmp[6] | ((unsigned int)tmp[7] << 16);
      *(uint4*)&dst[(size_t)c * dstride + dcol0 + r0 + ru * 8] = o;
    }
  }
}

// ---- pos4: pack (x,y,z,|p|^2); pad w=+INF; zero counts/cursor/nfail; cell hist ----
__global__ __launch_bounds__(256) void pos4_kernel(
    const float* __restrict__ pos, float4* __restrict__ pos4,
    int* __restrict__ counts, int* __restrict__ cursor,
    int* __restrict__ cellid, int* __restrict__ cellcnt,
    int* __restrict__ nfail)
{
  int c = blockIdx.x * 256 + threadIdx.x;      // grid 40 -> 10240 threads
  if (c == 0) *nfail = 0;
  if (c < POS4_PAD) {
    float4 v;
    if (c < N_NODES) {
      float x = pos[c * 3 + 0], y = pos[c * 3 + 1], z = pos[c * 3 + 2];
      v = make_float4(x, y, z, x * x + y * y + z * z);
      int cx = min(15, max(0, (int)floorf((x + 4.0f) * 2.0f)));
      int cy = min(15, max(0, (int)floorf((y + 4.0f) * 2.0f)));
      int cz = min(15, max(0, (int)floorf((z + 4.0f) * 2.0f)));
      int cell = (cx << 8) | (cy << 4) | cz;
      cellid[c] = cell;
      atomicAdd(&cellcnt[cell], 1);
      counts[c] = 0; cursor[c] = 0;
    } else {
      v = make_float4(0.f, 0.f, 0.f, __builtin_inff());   // d -> +INF
    }
    pos4[c] = v;
  }
}

// cell-histogram exclusive scan: 1 block, 16 cells/thread
__global__ __launch_bounds__(256) void cellscan_kernel(
    const int* __restrict__ cellcnt, int* __restrict__ cellptr)
{
  __shared__ int part[256];
  const int tid = threadIdx.x;
  const int base = tid * 16;
  int cv[16];
  int s = 0;
#pragma unroll
  for (int q = 0; q < 4; ++q) {
    int4 v = *(const int4*)&cellcnt[base + q * 4];
    cv[q * 4 + 0] = v.x; cv[q * 4 + 1] = v.y;
    cv[q * 4 + 2] = v.z; cv[q * 4 + 3] = v.w;
    s += v.x + v.y + v.z + v.w;
  }
  part[tid] = s;
  __syncthreads();
  for (int off = 1; off < 256; off <<= 1) {
    int add = (tid >= off) ? part[tid - off] : 0;
    __syncthreads();
    part[tid] += add;
    __syncthreads();
  }
  int run = part[tid] - s;
#pragma unroll
  for (int q = 0; q < 16; ++q) { cellptr[base + q] = run; run += cv[q]; }
  if (tid == 255) cellptr[NCELL] = run;
}

// counting-sort scatter: perm (cell-grouped node ids) + pos4s (sorted coords)
__global__ __launch_bounds__(256) void perm_kernel(
    const int* __restrict__ cellid, const int* __restrict__ cellptr,
    int* __restrict__ cellcur, int* __restrict__ perm,
    const float4* __restrict__ pos4, float4* __restrict__ pos4s)
{
  int c = blockIdx.x * 256 + threadIdx.x;
  if (c < N_NODES) {
    int cell = cellid[c];
    int p = atomicAdd(&cellcur[cell], 1);
    int slot = cellptr[cell] + p;
    perm[slot] = c;
    pos4s[slot] = pos4[c];
  }
}

// identical expression everywhere -> bit-identical distances
__device__ __forceinline__ float knn_dist(float4 pi, float4 s) {
  float dot = fmaf(pi.x, s.x, fmaf(pi.y, s.y, pi.z * s.z));
  return fmaf(-2.0f, dot, pi.w + s.w);
}

__device__ __forceinline__ void insert8(float r[8], float k) {
  // r ascending; r_j = median(k, r_{j-1}, r_j)
  asm("v_med3_f32 %0, %1, %2, %3" : "=v"(r[7]) : "v"(k), "v"(r[6]), "v"(r[7]));
  asm("v_med3_f32 %0, %1, %2, %3" : "=v"(r[6]) : "v"(k), "v"(r[5]), "v"(r[6]));
  asm("v_med3_f32 %0, %1, %2, %3" : "=v"(r[5]) : "v"(k), "v"(r[4]), "v"(r[5]));
  asm("v_med3_f32 %0, %1, %2, %3" : "=v"(r[4]) : "v"(k), "v"(r[3]), "v"(r[4]));
  asm("v_med3_f32 %0, %1, %2, %3" : "=v"(r[3]) : "v"(k), "v"(r[2]), "v"(r[3]));
  asm("v_med3_f32 %0, %1, %2, %3" : "=v"(r[2]) : "v"(k), "v"(r[1]), "v"(r[2]));
  asm("v_med3_f32 %0, %1, %2, %3" : "=v"(r[1]) : "v"(k), "v"(r[0]), "v"(r[1]));
  r[0] = fminf(r[0], k);
}

__device__ __forceinline__ float merge_tau20(float r[8], int lane) {
  const float INF = __builtin_inff();
  float tau = INF;
#pragma unroll
  for (int t = 0; t < KNN_K; ++t) {
    float m = r[0];
    m = fminf(m, __shfl_xor(m, 1));
    m = fminf(m, __shfl_xor(m, 2));
    m = fminf(m, __shfl_xor(m, 4));
    m = fminf(m, __shfl_xor(m, 8));
    m = fminf(m, __shfl_xor(m, 16));
    m = fminf(m, __shfl_xor(m, 32));
    unsigned long long who = __ballot(r[0] == m);
    int srcl = __ffsll(who) - 1;
    if (lane == srcl) {
#pragma unroll
      for (int z = 0; z < 7; ++z) r[z] = r[z + 1];
      r[7] = INF;
    }
    tau = m;
  }
  return tau;   // exact 20th smallest (INF if <20 candidates)
}

__device__ __forceinline__ void emit_hits(
    int i, bool valid, float d, float tau, int cid, int lane, int& cnt,
    int* __restrict__ knn_out)
{
  unsigned long long less = __ballot(valid && d < tau);
  unsigned long long eq   = __ballot(valid && d == tau);
  if (less) {
    if (valid && d < tau) {
      int pos = cnt + (int)__popcll(less & ((1ull << lane) - 1ull));
      if (pos < KNN_K) knn_out[i * KNN_K + pos] = cid;
    }
    cnt += (int)__popcll(less);
  }
  if (eq && cnt < KNN_K) {
    if (valid && d == tau) {
      int pos = cnt + (int)__popcll(eq & ((1ull << lane) - 1ull));
      if (pos < KNN_K) knn_out[i * KNN_K + pos] = cid;
    }
    cnt = min(KNN_K, cnt + (int)__popcll(eq));
  }
}

// ---------------- kNN try: 3^3 grid-pruned exact (round-10 path); else worklist ----------------
__global__ __launch_bounds__(256) void knn_try_kernel(
    const float4* __restrict__ pos4, const float4* __restrict__ pos4s,
    const int* __restrict__ perm, const int* __restrict__ cellptr,
    int* __restrict__ knn_out, int* __restrict__ wl, int* __restrict__ nfail)
{
  const int lane = threadIdx.x & 63, wave = threadIdx.x >> 6;
  const int wid = blockIdx.x * 4 + wave;
  const int i = perm[wid];                         // perm-ordered queries: L2 locality
  const float4 pi = pos4[i];
  const float INF = __builtin_inff();

  const int cx = min(15, max(0, (int)floorf((pi.x + 4.0f) * 2.0f)));
  const int cy = min(15, max(0, (int)floorf((pi.y + 4.0f) * 2.0f)));
  const int cz = min(15, max(0, (int)floorf((pi.z + 4.0f) * 2.0f)));
  const int x0 = max(cx - 1, 0), x1 = min(cx + 1, 15);
  const int y0 = max(cy - 1, 0), y1 = min(cy + 1, 15);
  const int z0 = max(cz - 1, 0), z1 = min(cz + 1, 15);

  float r[8];
#pragma unroll
  for (int q = 0; q < 8; ++q) r[q] = INF;

  // phase A: top-8 over the <=27-cell block (z-contiguous ranges)
  for (int X = x0; X <= x1; ++X)
    for (int Y = y0; Y <= y1; ++Y) {
      const int cb = (X << 8) | (Y << 4);
      const int s0 = cellptr[cb + z0], s1 = cellptr[cb + z1 + 1];
      for (int c0 = s0; c0 < s1; c0 += 64) {
        const int slot = c0 + lane;
        const int idx = min(slot, s1 - 1);
        const float4 s = pos4s[idx];
        const int nid = perm[idx];
        float d = knn_dist(pi, s);
        float k = (slot < s1 && nid != i) ? d : INF;
        insert8(r, k);
      }
    }
  float tau = merge_tau20(r, lane);

  // exactness margin: distance from query to scanned-region boundary
  float mx = INF, my = INF, mz = INF;
  if (x0 > 0)  mx = pi.x - (x0 * 0.5f - 4.0f);
  if (x1 < 15) mx = fminf(mx, ((x1 + 1) * 0.5f - 4.0f) - pi.x);
  if (y0 > 0)  my = pi.y - (y0 * 0.5f - 4.0f);
  if (y1 < 15) my = fminf(my, ((y1 + 1) * 0.5f - 4.0f) - pi.y);
  if (z0 > 0)  mz = pi.z - (z0 * 0.5f - 4.0f);
  if (z1 < 15) mz = fminf(mz, ((z1 + 1) * 0.5f - 4.0f) - pi.z);
  const float marg = fminf(mx, fminf(my, mz));

  if (tau < marg * marg) {
    // accepted: ball(sqrt(tau)) inside scanned region -> exact neighbor set
    int cnt = 0;
    for (int X = x0; X <= x1; ++X)
      for (int Y = y0; Y <= y1; ++Y) {
        const int cb = (X << 8) | (Y << 4);
        const int s0 = cellptr[cb + z0], s1 = cellptr[cb + z1 + 1];
        for (int c0 = s0; c0 < s1; c0 += 64) {
          const int slot = c0 + lane;
          const int idx = min(slot, s1 - 1);
          const float4 s = pos4s[idx];
          const int nid = perm[idx];
          float d = knn_dist(pi, s);
          bool valid = (slot < s1) && (nid != i);
          emit_hits(i, valid, d, tau, nid, lane, cnt, knn_out);
        }
      }
    return;
  }

  // failed: defer to knn_full (round-6 exact full scan)
  if (lane == 0) {
    int slot = atomicAdd(nfail, 1);
    wl[slot] = i;
  }
}

// ---------------- kNN full scan, block-per-query: 4 waves split the batches ----------------
__global__ __launch_bounds__(256) void knn_full_kernel(
    const float4* __restrict__ pos4, const int* __restrict__ wl,
    const int* __restrict__ nfail, int* __restrict__ knn_out)
{
  __shared__ float wmin[4];
  __shared__ int lcnt, eqcnt;
  __shared__ int eqbuf[64];
  const int tid = threadIdx.x;
  const int lane = tid & 63, wave = tid >> 6;
  const float INF = __builtin_inff();
  const int nf = *nfail;

  for (int w = blockIdx.x; w < nf; w += 2500) {
    const int i = wl[w];
    const float4 pi = pos4[i];

    // phase 1: wave `wave` scans batches b ≡ wave (mod 4); per-lane top-8
    float r[8];
#pragma unroll
    for (int q = 0; q < 8; ++q) r[q] = INF;
    for (int b = wave; b < NBATCH; b += 4) {
      const int cid = b * 64 + lane;
      const float4 s = pos4[cid];
      float d = knn_dist(pi, s);                  // pad rows: +INF
      float k = (cid == i) ? INF : d;
      insert8(r, k);
    }

    // block-level exact tau: 20 extract-min rounds across 4 waves
    float tau = INF;
#pragma unroll
    for (int t = 0; t < KNN_K; ++t) {
      float m = r[0];
      m = fminf(m, __shfl_xor(m, 1));
      m = fminf(m, __shfl_xor(m, 2));
      m = fminf(m, __shfl_xor(m, 4));
      m = fminf(m, __shfl_xor(m, 8));
      m = fminf(m, __shfl_xor(m, 16));
      m = fminf(m, __shfl_xor(m, 32));
      if (lane == 0) wmin[wave] = m;
      __syncthreads();
      float m0 = wmin[0], m1 = wmin[1], m2 = wmin[2], m3 = wmin[3];
      float gm = fminf(fminf(m0, m1), fminf(m2, m3));
      int wsel = (m0 == gm) ? 0 : ((m1 == gm) ? 1 : ((m2 == gm) ? 2 : 3));
      __syncthreads();                             // wmin consumed; safe for next round
      if (wave == wsel) {
        unsigned long long who = __ballot(r[0] == gm);
        int srcl = __ffsll(who) - 1;               // non-empty: wsel's min == gm
        if (lane == srcl) {
#pragma unroll
          for (int z = 0; z < 7; ++z) r[z] = r[z + 1];
          r[7] = INF;
        }
      }
      tau = gm;
    }

    // phase 2: emit. d<tau -> atomic unique slots (set-exact, order-free);
    // d==tau ties -> collect, sort by id, lowest-first fill to 20.
    if (tid == 0) { lcnt = 0; eqcnt = 0; }
    __syncthreads();
    for (int b = wave; b < NBATCH; b += 4) {
      const int cid = b * 64 + lane;
      const float4 s = pos4[cid];
      float d = knn_dist(pi, s);
      bool valid = (cid != i);                     // pad rows: d=INF, never accepted
      if (valid && d < tau) {
        int slot = atomicAdd(&lcnt, 1);
        if (slot < KNN_K) knn_out[i * KNN_K + slot] = cid;
      }
      if (valid && d == tau) {
        int e = atomicAdd(&eqcnt, 1);
        if (e < 64) eqbuf[e] = cid;
      }
    }
    __syncthreads();
    if (tid == 0) {
      int base = lcnt;                             // <= 19 (tau = 20th smallest)
      int ne = min(eqcnt, 64);
      for (int a = 1; a < ne; ++a) {               // tiny insertion sort by id
        int v = eqbuf[a];
        int b2 = a - 1;
        while (b2 >= 0 && eqbuf[b2] > v) { eqbuf[b2 + 1] = eqbuf[b2]; --b2; }
        eqbuf[b2 + 1] = v;
      }
      for (int q = 0; q < ne && base + q < KNN_K; ++q)
        knn_out[i * KNN_K + base + q] = eqbuf[q];
    }
    __syncthreads();                               // lcnt/eqcnt reused next iter
  }
}

// ---------------- reverse-CSR build ----------------
__global__ __launch_bounds__(256) void count_kernel(
    const int* __restrict__ knn, int* __restrict__ counts)
{
  int e = blockIdx.x * 256 + threadIdx.x;
  if (e < NEDGE) atomicAdd(&counts[knn[e]], 1);
}

// node-degree exclusive scan (int4 loads; 250 threads x 40 exact)
__global__ __launch_bounds__(256) void scan_kernel(
    const int* __restrict__ counts, int* __restrict__ rptr)
{
  __shared__ int part[256];
  const int tid = threadIdx.x;
  const int base = tid * 40;                       // 250*40 = 10000 exact
  int s = 0;
  int cv[40];
  if (tid < 250) {
#pragma unroll
    for (int q = 0; q < 10; ++q) {
      int4 v = *(const int4*)&counts[base + q * 4];
      cv[q * 4 + 0] = v.x; cv[q * 4 + 1] = v.y;
      cv[q * 4 + 2] = v.z; cv[q * 4 + 3] = v.w;
      s += v.x + v.y + v.z + v.w;
    }
  }
  part[tid] = s;
  __syncthreads();
  for (int off = 1; off < 256; off <<= 1) {
    int add = (tid >= off) ? part[tid - off] : 0;
    __syncthreads();
    part[tid] += add;
    __syncthreads();
  }
  int run = part[tid] - s;                         // exclusive offset
  if (tid < 250) {
#pragma unroll
    for (int q = 0; q < 40; ++q) { rptr[base + q] = run; run += cv[q]; }
  }
  if (tid == 255) rptr[N_NODES] = run;
}

__global__ __launch_bounds__(256) void fill_kernel(
    const int* __restrict__ knn, const int* __restrict__ rptr,
    int* __restrict__ cursor, int* __restrict__ rsrc)
{
  int e = blockIdx.x * 256 + threadIdx.x;
  if (e < NEDGE) {
    int j = knn[e];
    int i = e / KNN_K;
    int p = atomicAdd(&cursor[j], 1);
    rsrc[rptr[j] + p] = i;
  }
}

// sort each reverse-adjacency list ascending (bitonic-64 per wave)
__global__ __launch_bounds__(256) void sort_kernel(
    const int* __restrict__ rptr, int* __restrict__ rsrc)
{
  const int lane = threadIdx.x & 63, wave = threadIdx.x >> 6;
  const int j = blockIdx.x * 4 + wave;
  const int s0 = rptr[j], s1 = rptr[j + 1], deg = s1 - s0;
  if (deg <= 64) {
    int v = (lane < deg) ? rsrc[s0 + lane] : 0x7FFFFFFF;
#pragma unroll
    for (int k = 2; k <= 64; k <<= 1) {
#pragma unroll
      for (int m = k >> 1; m > 0; m >>= 1) {
        int other = __shfl_xor(v, m);
        bool up = ((lane & k) == 0);
        bool lower = ((lane & m) == 0);
        v = (up == lower) ? min(v, other) : max(v, other);
      }
    }
    if (lane < deg) rsrc[s0 + lane] = v;
  } else if (lane == 0) {
    for (int a = s0 + 1; a < s1; ++a) {
      int v = rsrc[a];
      int b = a - 1;
      while (b >= s0 && rsrc[b] > v) { rsrc[b + 1] = rsrc[b]; --b; }
      rsrc[b + 1] = v;
    }
  }
}

// ---------------- prop: out[j] = scale2 * sum_{i in rev(j)} t[i] - prev[j] ----------------
// XCD-chunked spatial schedule (perm is cell-sorted -> L2-local gathers)
__global__ __launch_bounds__(256) void prop_kernel(
    const unsigned short* __restrict__ tin, const unsigned short* __restrict__ tprev,
    unsigned short* __restrict__ tout, const int* __restrict__ rptr,
    const int* __restrict__ rsrc, const int* __restrict__ perm, float scale2)
{
  const int wave = threadIdx.x >> 6, lane = threadIdx.x & 63;
  const int b = blockIdx.x;                        // grid 2504
  const int xcd = b & 7, qb = b >> 3;
  const int local = qb * 4 + wave;
  if (local >= NPX) return;                        // no barriers below: safe
  const int j = perm[xcd * NPX + local];
  const int s0 = rptr[j], s1 = rptr[j + 1];
  const size_t coff = (size_t)lane * 8;

  float a0[8], a1[8], a2[8], a3[8];
#pragma unroll
  for (int q = 0; q < 8; ++q) { a0[q] = 0.f; a1[q] = 0.f; a2[q] = 0.f; a3[q] = 0.f; }

  for (int base = s0; base < s1; base += 64) {
    const int clen = min(64, s1 - base);
    int myidx = (base + lane < s1) ? rsrc[base + lane] : 0;
    int t = 0;
    for (; t + 4 <= clen; t += 4) {
      int i0 = __shfl(myidx, t);
      int i1 = __shfl(myidx, t + 1);
      int i2 = __shfl(myidx, t + 2);
      int i3 = __shfl(myidx, t + 3);
      uint4 v0 = *(const uint4*)&tin[(size_t)i0 * 512 + coff];
      uint4 v1 = *(const uint4*)&tin[(size_t)i1 * 512 + coff];
      uint4 v2 = *(const uint4*)&tin[(size_t)i2 * 512 + coff];
      uint4 v3 = *(const uint4*)&tin[(size_t)i3 * 512 + coff];
      a0[0] += bf_lo(v0.x); a0[1] += bf_hi(v0.x); a0[2] += bf_lo(v0.y); a0[3] += bf_hi(v0.y);
      a0[4] += bf_lo(v0.z); a0[5] += bf_hi(v0.z); a0[6] += bf_lo(v0.w); a0[7] += bf_hi(v0.w);
      a1[0] += bf_lo(v1.x); a1[1] += bf_hi(v1.x); a1[2] += bf_lo(v1.y); a1[3] += bf_hi(v1.y);
      a1[4] += bf_lo(v1.z); a1[5] += bf_hi(v1.z); a1[6] += bf_lo(v1.w); a1[7] += bf_hi(v1.w);
      a2[0] += bf_lo(v2.x); a2[1] += bf_hi(v2.x); a2[2] += bf_lo(v2.y); a2[3] += bf_hi(v2.y);
      a2[4] += bf_lo(v2.z); a2[5] += bf_hi(v2.z); a2[6] += bf_lo(v2.w); a2[7] += bf_hi(v2.w);
      a3[0] += bf_lo(v3.x); a3[1] += bf_hi(v3.x); a3[2] += bf_lo(v3.y); a3[3] += bf_hi(v3.y);
      a3[4] += bf_lo(v3.z); a3[5] += bf_hi(v3.z); a3[6] += bf_lo(v3.w); a3[7] += bf_hi(v3.w);
    }
    for (; t < clen; ++t) {
      int i0 = __shfl(myidx, t);
      uint4 v0 = *(const uint4*)&tin[(size_t)i0 * 512 + coff];
      a0[0] += bf_lo(v0.x); a0[1] += bf_hi(v0.x); a0[2] += bf_lo(v0.y); a0[3] += bf_hi(v0.y);
      a0[4] += bf_lo(v0.z); a0[5] += bf_hi(v0.z); a0[6] += bf_lo(v0.w); a0[7] += bf_hi(v0.w);
    }
  }

  float pv[8] = {0.f, 0.f, 0.f, 0.f, 0.f, 0.f, 0.f, 0.f};
  if (tprev != nullptr) {
    uint4 p = *(const uint4*)&tprev[(size_t)j * 512 + coff];
    pv[0] = bf_lo(p.x); pv[1] = bf_hi(p.x);
    pv[2] = bf_lo(p.y); pv[3] = bf_hi(p.y);
    pv[4] = bf_lo(p.z); pv[5] = bf_hi(p.z);
    pv[6] = bf_lo(p.w); pv[7] = bf_hi(p.w);
  }
  unsigned short o16[8];
#pragma unroll
  for (int q = 0; q < 8; ++q) {
    float acc = (a0[q] + a1[q]) + (a2[q] + a3[q]);   // fixed tree, deterministic
    o16[q] = f2bf(scale2 * acc - pv[q]);
  }
  uint4 o;
  o.x = (unsigned int)o16[0] | ((unsigned int)o16[1] << 16);
  o.y = (unsigned int)o16[2] | ((unsigned int)o16[3] << 16);
  o.z = (unsigned int)o16[4] | ((unsigned int)o16[5] << 16);
  o.w = (unsigned int)o16[6] | ((unsigned int)o16[7] << 16);
  *(uint4*)&tout[(size_t)j * 512 + coff] = o;
}

// ---------------- GEMM: C[o][n] = sum_kc A[n][kc] * B[kc][o] + bias[o] ----------------
// 64n x 128o tile, 628 blocks x 256 threads. A: double-buffered LDS (16KB) +
// counted-vmcnt(2) pipeline + T2 XOR swizzle. B: DIRECT L2->reg loads (theta^T
// is 2.6MB, L2-resident) — no B staging. Bijective XCD chunking.
__global__ __launch_bounds__(256) void gemm_kernel(
    const unsigned short* __restrict__ A,
    const unsigned short* __restrict__ Bt,
    const float* __restrict__ bias,
    float* __restrict__ C)
{
  __shared__ __align__(16) char smem[35840];          // 2 x As 8KB; epilogue 34.8KB
  float* eps = (float*)smem;                          // epilogue [128 o][68 n] f32

  const int tid = threadIdx.x;
  const int wave = tid >> 6, lane = tid & 63;
  const int l15 = lane & 15, hi = lane >> 4;

  // bijective XCD-chunked mapping of 628 (n,o) pairs, n-major
  const int bid = blockIdx.x;                         // 0..631
  const int xcd = bid & 7, local = bid >> 3;
  const int qd = GM_PAIRS >> 3, rem = GM_PAIRS & 7;   // 78, 4
  const int cnt = (xcd < rem) ? qd + 1 : qd;
  if (local >= cnt) return;                           // whole block exits: safe
  const int start = (xcd < rem) ? xcd * (qd + 1) : rem * (qd + 1) + (xcd - rem) * qd;
  const int pair = start + local;
  const int n0 = (pair >> 2) * 64;                    // 0..9984 (overread in pad)
  const int o0 = (pair & 3) * 128;

  f32x4 acc[4][2];
#pragma unroll
  for (int a = 0; a < 4; ++a)
#pragma unroll
    for (int b = 0; b < 2; ++b) acc[a][b] = (f32x4){0.f, 0.f, 0.f, 0.f};

  // stage A K-tile kt into buffer sel (2 gll16/thread).
  // LDS dest linear; global 16B-unit column pre-swizzled u_g = u ^ (r&7).
  auto stageA = [&](int kt, int sel) {
    const int k0 = kt * 64;
    const int ko = k0 >> 9;
    const int c0 = k0 & 511;
    const unsigned short* Ab = A + (size_t)ko * ((size_t)N_NODES * 512);
    unsigned short* As = (unsigned short*)(smem + sel * 8192);
#pragma unroll
    for (int q = 0; q < 2; ++q) {                     // 512 units
      int idx = (wave * 2 + q) * 64 + lane;
      int r = idx >> 3, u = idx & 7;
      int ug = u ^ (r & 7);
      gll16(Ab + (size_t)(n0 + r) * 512 + c0 + ug * 8, As + (size_t)(wave * 2 + q) * 512);
    }
  };

  stageA(0, 0);
  asm volatile("s_waitcnt vmcnt(0)" ::: "memory");     // tile 0 resident
  __builtin_amdgcn_s_barrier();

  for (int kt = 0; kt < 40; ++kt) {
    const int cur = kt & 1;
    const int k0c = kt * 64;
    // B fragments direct from L2-resident theta^T (issued FIRST: drained by
    // the vmcnt below together with tile-kt's A stage; only stage(kt+1) flies)
    bf16x8 bfr[2][2];
#pragma unroll
    for (int kk = 0; kk < 2; ++kk)
#pragma unroll
      for (int ni = 0; ni < 2; ++ni) {
        int o = o0 + wave * 32 + ni * 16 + l15;
        bfr[kk][ni] = *(const bf16x8*)(Bt + (size_t)o * 2560 + k0c + kk * 32 + hi * 8);
      }
    __builtin_amdgcn_sched_barrier(0);                 // pin issue order
    if (kt + 1 < 40) {
      stageA(kt + 1, cur ^ 1);                         // 2 loads join flight
      asm volatile("s_waitcnt vmcnt(2)" ::: "memory"); // B + tile-kt A complete
    } else {
      asm volatile("s_waitcnt vmcnt(0)" ::: "memory");
    }
    __builtin_amdgcn_s_barrier();                      // all waves: tile kt in LDS
    __builtin_amdgcn_sched_barrier(0);                 // pin ds_reads below
    unsigned short* As = (unsigned short*)(smem + cur * 8192);
#pragma unroll
    for (int kk = 0; kk < 2; ++kk) {
      bf16x8 af[4];
#pragma unroll
      for (int mi = 0; mi < 4; ++mi) {
        int row = mi * 16 + l15;                       // 0..63
        int up = (kk * 4 + hi) ^ (row & 7);            // read-side XOR
        af[mi] = *(const bf16x8*)(As + row * 64 + up * 8);
      }
#pragma unroll
      for (int mi = 0; mi < 4; ++mi)
#pragma unroll
        for (int ni = 0; ni < 2; ++ni)
          acc[mi][ni] = __builtin_amdgcn_mfma_f32_16x16x32_bf16(af[mi], bfr[kk][ni], acc[mi][ni], 0, 0, 0);
    }
    __builtin_amdgcn_s_barrier();                      // reads done before overwrite
  }

  // epilogue: waves own disjoint o-ranges -> single pass
  __syncthreads();                                     // protect smem from K-loop reuse
#pragma unroll
  for (int mi = 0; mi < 4; ++mi)
#pragma unroll
    for (int ni = 0; ni < 2; ++ni) {
      int o_l = wave * 32 + ni * 16 + l15;             // 0..127
      int nb = mi * 16 + hi * 4;                       // 0..60
      *(f32x4*)&eps[o_l * 68 + nb] = acc[mi][ni];
    }
  __syncthreads();
#pragma unroll
  for (int q = 0; q < 8; ++q) {
    int unit = q * 256 + tid;                          // 2048 float4 units
    int o_l = unit >> 4, nu = unit & 15;
    int n = n0 + nu * 4;
    if (n < N_NODES) {
      int o = o0 + o_l;
      f32x4 v = *(const f32x4*)&eps[o_l * 68 + nu * 4];
      float bo = bias[o];
      v = v + bo;
      *(f32x4*)&C[(size_t)o * N_NODES + n] = v;
    }
  }
}

extern "C" void kernel_launch(void* const* d_in, const int* in_sizes, int n_in,
                              void* d_out, int out_size, void* d_ws, size_t ws_size,
                              hipStream_t stream)
{
  const float* x        = (const float*)d_in[0];   // [512][10000]
  const float* position = (const float*)d_in[1];   // [10000][3]
  const float* theta    = (const float*)d_in[2];   // [5][512][512]
  const float* bias     = (const float*)d_in[3];   // [512]

  char* ws = (char*)d_ws;
  size_t off = 0;
  auto alloc = [&](size_t bytes) -> void* {
    void* p = ws + off;
    off = (off + bytes + 255) & ~(size_t)255;
    return p;
  };
  unsigned short* TxAll   = (unsigned short*)alloc(5ull * N_NODES * 512 * 2 + 131072); // +128-row pad
  unsigned short* thetabT = (unsigned short*)alloc(512ull * 2560 * 2);
  float4* pos4  = (float4*)alloc((size_t)POS4_PAD * 16);
  float4* pos4s = (float4*)alloc((size_t)N_NODES * 16);
  int* knn    = (int*)alloc((size_t)NEDGE * 4);
  int* rptr   = (int*)alloc((size_t)(N_NODES + 1) * 4);
  int* counts = (int*)alloc((size_t)N_NODES * 4);
  int* cursor = (int*)alloc((size_t)N_NODES * 4);
  int* rsrc   = (int*)alloc((size_t)NEDGE * 4);
  int* cellcnt = (int*)alloc((size_t)NCELL * 4);   // contiguous with cellcur:
  int* cellcur = (int*)alloc((size_t)NCELL * 4);   // zeroed by theta-transpose
  int* cellptr = (int*)alloc((size_t)(NCELL + 1) * 4);
  int* cellid  = (int*)alloc((size_t)N_NODES * 4);
  int* perm    = (int*)alloc((size_t)N_NODES * 4);
  int* wl      = (int*)alloc((size_t)N_NODES * 4);
  int* nfail   = (int*)alloc(256);
  if (ws_size < off) return;   // insufficient scratch

  // theta [5][512][512] -> thetabT [o=512][kc=2560]; also zeroes cellcnt+cellcur
  transpose_f32_bf16<<<dim3(8, 8, 5), 256, 0, stream>>>(
      theta, thetabT, 512, 512, 2560, (size_t)512 * 512, 512, cellcnt);
  // x [512][10000] -> Tx0 [10000][512]
  transpose_f32_bf16<<<dim3(157, 8, 1), 256, 0, stream>>>(
      x, TxAll, 512, N_NODES, 512, 0, 0, nullptr);

  pos4_kernel<<<40, 256, 0, stream>>>(position, pos4, counts, cursor, cellid, cellcnt, nfail);
  cellscan_kernel<<<1, 256, 0, stream>>>(cellcnt, cellptr);
  perm_kernel<<<40, 256, 0, stream>>>(cellid, cellptr, cellcur, perm, pos4, pos4s);

  knn_try_kernel<<<2500, 256, 0, stream>>>(pos4, pos4s, perm, cellptr, knn, wl, nfail);
  knn_full_kernel<<<2500, 256, 0, stream>>>(pos4, wl, nfail, knn);

  count_kernel<<<(NEDGE + 255) / 256, 256, 0, stream>>>(knn, counts);
  scan_kernel<<<1, 256, 0, stream>>>(counts, rptr);
  fill_kernel<<<(NEDGE + 255) / 256, 256, 0, stream>>>(knn, rptr, cursor, rsrc);
  sort_kernel<<<2500, 256, 0, stream>>>(rptr, rsrc);

  unsigned short* Tx0 = TxAll;
  unsigned short* Tx1 = TxAll + 1ull * N_NODES * 512;
  unsigned short* Tx2 = TxAll + 2ull * N_NODES * 512;
  unsigned short* Tx3 = TxAll + 3ull * N_NODES * 512;
  unsigned short* Tx4 = TxAll + 4ull * N_NODES * 512;

  // Tx1 = prop(Tx0) = -0.05*sum ; Tx_k = 2*prop(Tx_{k-1}) - Tx_{k-2} = -0.10*sum - prev
  prop_kernel<<<2504, 256, 0, stream>>>(Tx0, nullptr, Tx1, rptr, rsrc, perm, -0.05f);
  prop_kernel<<<2504, 256, 0, stream>>>(Tx1, Tx0,     Tx2, rptr, rsrc, perm, -0.10f);
  prop_kernel<<<2504, 256, 0, stream>>>(Tx2, Tx1,     Tx3, rptr, rsrc, perm, -0.10f);
  prop_kernel<<<2504, 256, 0, stream>>>(Tx3, Tx2,     Tx4, rptr, rsrc, perm, -0.10f);

  gemm_kernel<<<632, 256, 0, stream>>>(TxAll, thetabT, bias, (float*)d_out);
}

// Round 20
// 222.995 us; speedup vs baseline: 1.1535x; 1.1535x over previous
//
// Round 20: REVERT gemm to round-16 exact (B-direct r19 was 64-way uncoalesced:
// lanes stride 5120B => 75.6us). Keep r19's memset-fold (one fewer dispatch).
// This is the best-known configuration: r16 = 224.9us total, gemm 41.1us.
#include <hip/hip_runtime.h>
#include <hip/hip_bf16.h>
#include <cstdint>
#include <cstddef>

#define N_NODES 10000
#define KNN_K 20
#define NEDGE (N_NODES * KNN_K)
#define NBATCH 157                 // ceil(10000/64)
#define POS4_PAD 10048             // 157*64
#define NCELL 4096                 // 16x16x16 spatial cells, h=0.5
#define NPX 1250                   // nodes per XCD chunk (10000/8)
#define GM_PAIRS 628               // 157 n-tiles (64) x 4 o-tiles (128)

using bf16x8 = __attribute__((ext_vector_type(8))) short;
using f32x4  = __attribute__((ext_vector_type(4))) float;

__device__ __forceinline__ float bf_lo(unsigned int u) {
  union { unsigned int i; float f; } c; c.i = u << 16; return c.f;
}
__device__ __forceinline__ float bf_hi(unsigned int u) {
  union { unsigned int i; float f; } c; c.i = u & 0xFFFF0000u; return c.f;
}
__device__ __forceinline__ unsigned short f2bf(float f) {
  union { float f; unsigned int i; } c; c.f = f;
  unsigned int u = c.i;
  u += 0x7FFFu + ((u >> 16) & 1u);   // RNE
  return (unsigned short)(u >> 16);
}

__device__ __forceinline__ void gll16(const void* g, void* l) {
  __builtin_amdgcn_global_load_lds(
      (const __attribute__((address_space(1))) unsigned int*)g,
      (__attribute__((address_space(3))) unsigned int*)l,
      16, 0, 0);
}

// ---------------- transpose f32 [srows][scols] -> bf16 dst[col][dcol0 + row] ----------------
// zbuf: if non-null, blocks (z==0,y==0,x<8) zero zbuf[0..8191] (cellcnt+cellcur)
__global__ __launch_bounds__(256) void transpose_f32_bf16(
    const float* __restrict__ src0, unsigned short* __restrict__ dst,
    int srows, int scols, int dstride, size_t slice_elems, int dcol_per_slice,
    int* __restrict__ zbuf)
{
  __shared__ float lds[64 * 65];
  const int z = blockIdx.z;
  if (zbuf != nullptr && z == 0 && blockIdx.y == 0 && blockIdx.x < 8) {
    int4 zz = make_int4(0, 0, 0, 0);
    *(int4*)&zbuf[(blockIdx.x * 256 + threadIdx.x) * 4] = zz;
  }
  const float* src = src0 + (size_t)z * slice_elems;
  const int dcol0 = z * dcol_per_slice;
  const int c0 = blockIdx.x * 64;
  const int r0 = blockIdx.y * 64;
  const int tid = threadIdx.x;
#pragma unroll
  for (int q = 0; q < 4; ++q) {
    int unit = q * 256 + tid;            // 1024 float4 units
    int rr = unit >> 4;                  // 0..63
    int cu = unit & 15;                  // 0..15
    int r = r0 + rr, c = c0 + cu * 4;
    float4 v = make_float4(0.f, 0.f, 0.f, 0.f);
    if (r < srows && c + 3 < scols) v = *(const float4*)&src[(size_t)r * scols + c];
    lds[rr * 65 + cu * 4 + 0] = v.x;
    lds[rr * 65 + cu * 4 + 1] = v.y;
    lds[rr * 65 + cu * 4 + 2] = v.z;
    lds[rr * 65 + cu * 4 + 3] = v.w;
  }
  __syncthreads();
#pragma unroll
  for (int q = 0; q < 2; ++q) {
    int unit = q * 256 + tid;            // 512 units of 8 bf16
    int cl = unit >> 3;                  // src col within tile (= dst row)
    int ru = unit & 7;
    int c = c0 + cl;
    if (c < scols) {
      unsigned short tmp[8];
#pragma unroll
      for (int j = 0; j < 8; ++j) tmp[j] = f2bf(lds[(ru * 8 + j) * 65 + cl]);
      uint4 o;
      o.x = (unsigned int)tmp[0] | ((unsigned int)tmp[1] << 16);
      o.y = (unsigned int)tmp[2] | ((unsigned int)tmp[3] << 16);
      o.z = (unsigned int)tmp[4] | ((unsigned int)tmp[5] << 16);
      o.w = (unsigned int)tmp[6] | ((unsigned int)tmp[7] << 16);
      *(uint4*)&dst[(size_t)c * dstride + dcol0 + r0 + ru * 8] = o;
    }
  }
}

// ---- pos4: pack (x,y,z,|p|^2); pad w=+INF; zero counts/cursor/nfail; cell hist ----
__global__ __launch_bounds__(256) void pos4_kernel(
    const float* __restrict__ pos, float4* __restrict__ pos4,
    int* __restrict__ counts, int* __restrict__ cursor,
    int* __restrict__ cellid, int* __restrict__ cellcnt,
    int* __restrict__ nfail)
{
  int c = blockIdx.x * 256 + threadIdx.x;      // grid 40 -> 10240 threads
  if (c == 0) *nfail = 0;
  if (c < POS4_PAD) {
    float4 v;
    if (c < N_NODES) {
      float x = pos[c * 3 + 0], y = pos[c * 3 + 1], z = pos[c * 3 + 2];
      v = make_float4(x, y, z, x * x + y * y + z * z);
      int cx = min(15, max(0, (int)floorf((x + 4.0f) * 2.0f)));
      int cy = min(15, max(0, (int)floorf((y + 4.0f) * 2.0f)));
      int cz = min(15, max(0, (int)floorf((z + 4.0f) * 2.0f)));
      int cell = (cx << 8) | (cy << 4) | cz;
      cellid[c] = cell;
      atomicAdd(&cellcnt[cell], 1);
      counts[c] = 0; cursor[c] = 0;
    } else {
      v = make_float4(0.f, 0.f, 0.f, __builtin_inff());   // d -> +INF
    }
    pos4[c] = v;
  }
}

// cell-histogram exclusive scan: 1 block, 16 cells/thread
__global__ __launch_bounds__(256) void cellscan_kernel(
    const int* __restrict__ cellcnt, int* __restrict__ cellptr)
{
  __shared__ int part[256];
  const int tid = threadIdx.x;
  const int base = tid * 16;
  int cv[16];
  int s = 0;
#pragma unroll
  for (int q = 0; q < 4; ++q) {
    int4 v = *(const int4*)&cellcnt[base + q * 4];
    cv[q * 4 + 0] = v.x; cv[q * 4 + 1] = v.y;
    cv[q * 4 + 2] = v.z; cv[q * 4 + 3] = v.w;
    s += v.x + v.y + v.z + v.w;
  }
  part[tid] = s;
  __syncthreads();
  for (int off = 1; off < 256; off <<= 1) {
    int add = (tid >= off) ? part[tid - off] : 0;
    __syncthreads();
    part[tid] += add;
    __syncthreads();
  }
  int run = part[tid] - s;
#pragma unroll
  for (int q = 0; q < 16; ++q) { cellptr[base + q] = run; run += cv[q]; }
  if (tid == 255) cellptr[NCELL] = run;
}

// counting-sort scatter: perm (cell-grouped node ids) + pos4s (sorted coords)
__global__ __launch_bounds__(256) void perm_kernel(
    const int* __restrict__ cellid, const int* __restrict__ cellptr,
    int* __restrict__ cellcur, int* __restrict__ perm,
    const float4* __restrict__ pos4, float4* __restrict__ pos4s)
{
  int c = blockIdx.x * 256 + threadIdx.x;
  if (c < N_NODES) {
    int cell = cellid[c];
    int p = atomicAdd(&cellcur[cell], 1);
    int slot = cellptr[cell] + p;
    perm[slot] = c;
    pos4s[slot] = pos4[c];
  }
}

// identical expression everywhere -> bit-identical distances
__device__ __forceinline__ float knn_dist(float4 pi, float4 s) {
  float dot = fmaf(pi.x, s.x, fmaf(pi.y, s.y, pi.z * s.z));
  return fmaf(-2.0f, dot, pi.w + s.w);
}

__device__ __forceinline__ void insert8(float r[8], float k) {
  // r ascending; r_j = median(k, r_{j-1}, r_j)
  asm("v_med3_f32 %0, %1, %2, %3" : "=v"(r[7]) : "v"(k), "v"(r[6]), "v"(r[7]));
  asm("v_med3_f32 %0, %1, %2, %3" : "=v"(r[6]) : "v"(k), "v"(r[5]), "v"(r[6]));
  asm("v_med3_f32 %0, %1, %2, %3" : "=v"(r[5]) : "v"(k), "v"(r[4]), "v"(r[5]));
  asm("v_med3_f32 %0, %1, %2, %3" : "=v"(r[4]) : "v"(k), "v"(r[3]), "v"(r[4]));
  asm("v_med3_f32 %0, %1, %2, %3" : "=v"(r[3]) : "v"(k), "v"(r[2]), "v"(r[3]));
  asm("v_med3_f32 %0, %1, %2, %3" : "=v"(r[2]) : "v"(k), "v"(r[1]), "v"(r[2]));
  asm("v_med3_f32 %0, %1, %2, %3" : "=v"(r[1]) : "v"(k), "v"(r[0]), "v"(r[1]));
  r[0] = fminf(r[0], k);
}

__device__ __forceinline__ float merge_tau20(float r[8], int lane) {
  const float INF = __builtin_inff();
  float tau = INF;
#pragma unroll
  for (int t = 0; t < KNN_K; ++t) {
    float m = r[0];
    m = fminf(m, __shfl_xor(m, 1));
    m = fminf(m, __shfl_xor(m, 2));
    m = fminf(m, __shfl_xor(m, 4));
    m = fminf(m, __shfl_xor(m, 8));
    m = fminf(m, __shfl_xor(m, 16));
    m = fminf(m, __shfl_xor(m, 32));
    unsigned long long who = __ballot(r[0] == m);
    int srcl = __ffsll(who) - 1;
    if (lane == srcl) {
#pragma unroll
      for (int z = 0; z < 7; ++z) r[z] = r[z + 1];
      r[7] = INF;
    }
    tau = m;
  }
  return tau;   // exact 20th smallest (INF if <20 candidates)
}

__device__ __forceinline__ void emit_hits(
    int i, bool valid, float d, float tau, int cid, int lane, int& cnt,
    int* __restrict__ knn_out)
{
  unsigned long long less = __ballot(valid && d < tau);
  unsigned long long eq   = __ballot(valid && d == tau);
  if (less) {
    if (valid && d < tau) {
      int pos = cnt + (int)__popcll(less & ((1ull << lane) - 1ull));
      if (pos < KNN_K) knn_out[i * KNN_K + pos] = cid;
    }
    cnt += (int)__popcll(less);
  }
  if (eq && cnt < KNN_K) {
    if (valid && d == tau) {
      int pos = cnt + (int)__popcll(eq & ((1ull << lane) - 1ull));
      if (pos < KNN_K) knn_out[i * KNN_K + pos] = cid;
    }
    cnt = min(KNN_K, cnt + (int)__popcll(eq));
  }
}

// ---------------- kNN try: 3^3 grid-pruned exact (round-10 path); else worklist ----------------
__global__ __launch_bounds__(256) void knn_try_kernel(
    const float4* __restrict__ pos4, const float4* __restrict__ pos4s,
    const int* __restrict__ perm, const int* __restrict__ cellptr,
    int* __restrict__ knn_out, int* __restrict__ wl, int* __restrict__ nfail)
{
  const int lane = threadIdx.x & 63, wave = threadIdx.x >> 6;
  const int wid = blockIdx.x * 4 + wave;
  const int i = perm[wid];                         // perm-ordered queries: L2 locality
  const float4 pi = pos4[i];
  const float INF = __builtin_inff();

  const int cx = min(15, max(0, (int)floorf((pi.x + 4.0f) * 2.0f)));
  const int cy = min(15, max(0, (int)floorf((pi.y + 4.0f) * 2.0f)));
  const int cz = min(15, max(0, (int)floorf((pi.z + 4.0f) * 2.0f)));
  const int x0 = max(cx - 1, 0), x1 = min(cx + 1, 15);
  const int y0 = max(cy - 1, 0), y1 = min(cy + 1, 15);
  const int z0 = max(cz - 1, 0), z1 = min(cz + 1, 15);

  float r[8];
#pragma unroll
  for (int q = 0; q < 8; ++q) r[q] = INF;

  // phase A: top-8 over the <=27-cell block (z-contiguous ranges)
  for (int X = x0; X <= x1; ++X)
    for (int Y = y0; Y <= y1; ++Y) {
      const int cb = (X << 8) | (Y << 4);
      const int s0 = cellptr[cb + z0], s1 = cellptr[cb + z1 + 1];
      for (int c0 = s0; c0 < s1; c0 += 64) {
        const int slot = c0 + lane;
        const int idx = min(slot, s1 - 1);
        const float4 s = pos4s[idx];
        const int nid = perm[idx];
        float d = knn_dist(pi, s);
        float k = (slot < s1 && nid != i) ? d : INF;
        insert8(r, k);
      }
    }
  float tau = merge_tau20(r, lane);

  // exactness margin: distance from query to scanned-region boundary
  float mx = INF, my = INF, mz = INF;
  if (x0 > 0)  mx = pi.x - (x0 * 0.5f - 4.0f);
  if (x1 < 15) mx = fminf(mx, ((x1 + 1) * 0.5f - 4.0f) - pi.x);
  if (y0 > 0)  my = pi.y - (y0 * 0.5f - 4.0f);
  if (y1 < 15) my = fminf(my, ((y1 + 1) * 0.5f - 4.0f) - pi.y);
  if (z0 > 0)  mz = pi.z - (z0 * 0.5f - 4.0f);
  if (z1 < 15) mz = fminf(mz, ((z1 + 1) * 0.5f - 4.0f) - pi.z);
  const float marg = fminf(mx, fminf(my, mz));

  if (tau < marg * marg) {
    // accepted: ball(sqrt(tau)) inside scanned region -> exact neighbor set
    int cnt = 0;
    for (int X = x0; X <= x1; ++X)
      for (int Y = y0; Y <= y1; ++Y) {
        const int cb = (X << 8) | (Y << 4);
        const int s0 = cellptr[cb + z0], s1 = cellptr[cb + z1 + 1];
        for (int c0 = s0; c0 < s1; c0 += 64) {
          const int slot = c0 + lane;
          const int idx = min(slot, s1 - 1);
          const float4 s = pos4s[idx];
          const int nid = perm[idx];
          float d = knn_dist(pi, s);
          bool valid = (slot < s1) && (nid != i);
          emit_hits(i, valid, d, tau, nid, lane, cnt, knn_out);
        }
      }
    return;
  }

  // failed: defer to knn_full (round-6 exact full scan)
  if (lane == 0) {
    int slot = atomicAdd(nfail, 1);
    wl[slot] = i;
  }
}

// ---------------- kNN full scan, block-per-query: 4 waves split the batches ----------------
__global__ __launch_bounds__(256) void knn_full_kernel(
    const float4* __restrict__ pos4, const int* __restrict__ wl,
    const int* __restrict__ nfail, int* __restrict__ knn_out)
{
  __shared__ float wmin[4];
  __shared__ int lcnt, eqcnt;
  __shared__ int eqbuf[64];
  const int tid = threadIdx.x;
  const int lane = tid & 63, wave = tid >> 6;
  const float INF = __builtin_inff();
  const int nf = *nfail;

  for (int w = blockIdx.x; w < nf; w += 2500) {
    const int i = wl[w];
    const float4 pi = pos4[i];

    // phase 1: wave `wave` scans batches b ≡ wave (mod 4); per-lane top-8
    float r[8];
#pragma unroll
    for (int q = 0; q < 8; ++q) r[q] = INF;
    for (int b = wave; b < NBATCH; b += 4) {
      const int cid = b * 64 + lane;
      const float4 s = pos4[cid];
      float d = knn_dist(pi, s);                  // pad rows: +INF
      float k = (cid == i) ? INF : d;
      insert8(r, k);
    }

    // block-level exact tau: 20 extract-min rounds across 4 waves
    float tau = INF;
#pragma unroll
    for (int t = 0; t < KNN_K; ++t) {
      float m = r[0];
      m = fminf(m, __shfl_xor(m, 1));
      m = fminf(m, __shfl_xor(m, 2));
      m = fminf(m, __shfl_xor(m, 4));
      m = fminf(m, __shfl_xor(m, 8));
      m = fminf(m, __shfl_xor(m, 16));
      m = fminf(m, __shfl_xor(m, 32));
      if (lane == 0) wmin[wave] = m;
      __syncthreads();
      float m0 = wmin[0], m1 = wmin[1], m2 = wmin[2], m3 = wmin[3];
      float gm = fminf(fminf(m0, m1), fminf(m2, m3));
      int wsel = (m0 == gm) ? 0 : ((m1 == gm) ? 1 : ((m2 == gm) ? 2 : 3));
      __syncthreads();                             // wmin consumed; safe for next round
      if (wave == wsel) {
        unsigned long long who = __ballot(r[0] == gm);
        int srcl = __ffsll(who) - 1;               // non-empty: wsel's min == gm
        if (lane == srcl) {
#pragma unroll
          for (int z = 0; z < 7; ++z) r[z] = r[z + 1];
          r[7] = INF;
        }
      }
      tau = gm;
    }

    // phase 2: emit. d<tau -> atomic unique slots (set-exact, order-free);
    // d==tau ties -> collect, sort by id, lowest-first fill to 20.
    if (tid == 0) { lcnt = 0; eqcnt = 0; }
    __syncthreads();
    for (int b = wave; b < NBATCH; b += 4) {
      const int cid = b * 64 + lane;
      const float4 s = pos4[cid];
      float d = knn_dist(pi, s);
      bool valid = (cid != i);                     // pad rows: d=INF, never accepted
      if (valid && d < tau) {
        int slot = atomicAdd(&lcnt, 1);
        if (slot < KNN_K) knn_out[i * KNN_K + slot] = cid;
      }
      if (valid && d == tau) {
        int e = atomicAdd(&eqcnt, 1);
        if (e < 64) eqbuf[e] = cid;
      }
    }
    __syncthreads();
    if (tid == 0) {
      int base = lcnt;                             // <= 19 (tau = 20th smallest)
      int ne = min(eqcnt, 64);
      for (int a = 1; a < ne; ++a) {               // tiny insertion sort by id
        int v = eqbuf[a];
        int b2 = a - 1;
        while (b2 >= 0 && eqbuf[b2] > v) { eqbuf[b2 + 1] = eqbuf[b2]; --b2; }
        eqbuf[b2 + 1] = v;
      }
      for (int q = 0; q < ne && base + q < KNN_K; ++q)
        knn_out[i * KNN_K + base + q] = eqbuf[q];
    }
    __syncthreads();                               // lcnt/eqcnt reused next iter
  }
}

// ---------------- reverse-CSR build ----------------
__global__ __launch_bounds__(256) void count_kernel(
    const int* __restrict__ knn, int* __restrict__ counts)
{
  int e = blockIdx.x * 256 + threadIdx.x;
  if (e < NEDGE) atomicAdd(&counts[knn[e]], 1);
}

// node-degree exclusive scan (int4 loads; 250 threads x 40 exact)
__global__ __launch_bounds__(256) void scan_kernel(
    const int* __restrict__ counts, int* __restrict__ rptr)
{
  __shared__ int part[256];
  const int tid = threadIdx.x;
  const int base = tid * 40;                       // 250*40 = 10000 exact
  int s = 0;
  int cv[40];
  if (tid < 250) {
#pragma unroll
    for (int q = 0; q < 10; ++q) {
      int4 v = *(const int4*)&counts[base + q * 4];
      cv[q * 4 + 0] = v.x; cv[q * 4 + 1] = v.y;
      cv[q * 4 + 2] = v.z; cv[q * 4 + 3] = v.w;
      s += v.x + v.y + v.z + v.w;
    }
  }
  part[tid] = s;
  __syncthreads();
  for (int off = 1; off < 256; off <<= 1) {
    int add = (tid >= off) ? part[tid - off] : 0;
    __syncthreads();
    part[tid] += add;
    __syncthreads();
  }
  int run = part[tid] - s;                         // exclusive offset
  if (tid < 250) {
#pragma unroll
    for (int q = 0; q < 40; ++q) { rptr[base + q] = run; run += cv[q]; }
  }
  if (tid == 255) rptr[N_NODES] = run;
}

__global__ __launch_bounds__(256) void fill_kernel(
    const int* __restrict__ knn, const int* __restrict__ rptr,
    int* __restrict__ cursor, int* __restrict__ rsrc)
{
  int e = blockIdx.x * 256 + threadIdx.x;
  if (e < NEDGE) {
    int j = knn[e];
    int i = e / KNN_K;
    int p = atomicAdd(&cursor[j], 1);
    rsrc[rptr[j] + p] = i;
  }
}

// sort each reverse-adjacency list ascending (bitonic-64 per wave)
__global__ __launch_bounds__(256) void sort_kernel(
    const int* __restrict__ rptr, int* __restrict__ rsrc)
{
  const int lane = threadIdx.x & 63, wave = threadIdx.x >> 6;
  const int j = blockIdx.x * 4 + wave;
  const int s0 = rptr[j], s1 = rptr[j + 1], deg = s1 - s0;
  if (deg <= 64) {
    int v = (lane < deg) ? rsrc[s0 + lane] : 0x7FFFFFFF;
#pragma unroll
    for (int k = 2; k <= 64; k <<= 1) {
#pragma unroll
      for (int m = k >> 1; m > 0; m >>= 1) {
        int other = __shfl_xor(v, m);
        bool up = ((lane & k) == 0);
        bool lower = ((lane & m) == 0);
        v = (up == lower) ? min(v, other) : max(v, other);
      }
    }
    if (lane < deg) rsrc[s0 + lane] = v;
  } else if (lane == 0) {
    for (int a = s0 + 1; a < s1; ++a) {
      int v = rsrc[a];
      int b = a - 1;
      while (b >= s0 && rsrc[b] > v) { rsrc[b + 1] = rsrc[b]; --b; }
      rsrc[b + 1] = v;
    }
  }
}

// ---------------- prop: out[j] = scale2 * sum_{i in rev(j)} t[i] - prev[j] ----------------
// XCD-chunked spatial schedule (perm is cell-sorted -> L2-local gathers)
__global__ __launch_bounds__(256) void prop_kernel(
    const unsigned short* __restrict__ tin, const unsigned short* __restrict__ tprev,
    unsigned short* __restrict__ tout, const int* __restrict__ rptr,
    const int* __restrict__ rsrc, const int* __restrict__ perm, float scale2)
{
  const int wave = threadIdx.x >> 6, lane = threadIdx.x & 63;
  const int b = blockIdx.x;                        // grid 2504
  const int xcd = b & 7, qb = b >> 3;
  const int local = qb * 4 + wave;
  if (local >= NPX) return;                        // no barriers below: safe
  const int j = perm[xcd * NPX + local];
  const int s0 = rptr[j], s1 = rptr[j + 1];
  const size_t coff = (size_t)lane * 8;

  float a0[8], a1[8], a2[8], a3[8];
#pragma unroll
  for (int q = 0; q < 8; ++q) { a0[q] = 0.f; a1[q] = 0.f; a2[q] = 0.f; a3[q] = 0.f; }

  for (int base = s0; base < s1; base += 64) {
    const int clen = min(64, s1 - base);
    int myidx = (base + lane < s1) ? rsrc[base + lane] : 0;
    int t = 0;
    for (; t + 4 <= clen; t += 4) {
      int i0 = __shfl(myidx, t);
      int i1 = __shfl(myidx, t + 1);
      int i2 = __shfl(myidx, t + 2);
      int i3 = __shfl(myidx, t + 3);
      uint4 v0 = *(const uint4*)&tin[(size_t)i0 * 512 + coff];
      uint4 v1 = *(const uint4*)&tin[(size_t)i1 * 512 + coff];
      uint4 v2 = *(const uint4*)&tin[(size_t)i2 * 512 + coff];
      uint4 v3 = *(const uint4*)&tin[(size_t)i3 * 512 + coff];
      a0[0] += bf_lo(v0.x); a0[1] += bf_hi(v0.x); a0[2] += bf_lo(v0.y); a0[3] += bf_hi(v0.y);
      a0[4] += bf_lo(v0.z); a0[5] += bf_hi(v0.z); a0[6] += bf_lo(v0.w); a0[7] += bf_hi(v0.w);
      a1[0] += bf_lo(v1.x); a1[1] += bf_hi(v1.x); a1[2] += bf_lo(v1.y); a1[3] += bf_hi(v1.y);
      a1[4] += bf_lo(v1.z); a1[5] += bf_hi(v1.z); a1[6] += bf_lo(v1.w); a1[7] += bf_hi(v1.w);
      a2[0] += bf_lo(v2.x); a2[1] += bf_hi(v2.x); a2[2] += bf_lo(v2.y); a2[3] += bf_hi(v2.y);
      a2[4] += bf_lo(v2.z); a2[5] += bf_hi(v2.z); a2[6] += bf_lo(v2.w); a2[7] += bf_hi(v2.w);
      a3[0] += bf_lo(v3.x); a3[1] += bf_hi(v3.x); a3[2] += bf_lo(v3.y); a3[3] += bf_hi(v3.y);
      a3[4] += bf_lo(v3.z); a3[5] += bf_hi(v3.z); a3[6] += bf_lo(v3.w); a3[7] += bf_hi(v3.w);
    }
    for (; t < clen; ++t) {
      int i0 = __shfl(myidx, t);
      uint4 v0 = *(const uint4*)&tin[(size_t)i0 * 512 + coff];
      a0[0] += bf_lo(v0.x); a0[1] += bf_hi(v0.x); a0[2] += bf_lo(v0.y); a0[3] += bf_hi(v0.y);
      a0[4] += bf_lo(v0.z); a0[5] += bf_hi(v0.z); a0[6] += bf_lo(v0.w); a0[7] += bf_hi(v0.w);
    }
  }

  float pv[8] = {0.f, 0.f, 0.f, 0.f, 0.f, 0.f, 0.f, 0.f};
  if (tprev != nullptr) {
    uint4 p = *(const uint4*)&tprev[(size_t)j * 512 + coff];
    pv[0] = bf_lo(p.x); pv[1] = bf_hi(p.x);
    pv[2] = bf_lo(p.y); pv[3] = bf_hi(p.y);
    pv[4] = bf_lo(p.z); pv[5] = bf_hi(p.z);
    pv[6] = bf_lo(p.w); pv[7] = bf_hi(p.w);
  }
  unsigned short o16[8];
#pragma unroll
  for (int q = 0; q < 8; ++q) {
    float acc = (a0[q] + a1[q]) + (a2[q] + a3[q]);   // fixed tree, deterministic
    o16[q] = f2bf(scale2 * acc - pv[q]);
  }
  uint4 o;
  o.x = (unsigned int)o16[0] | ((unsigned int)o16[1] << 16);
  o.y = (unsigned int)o16[2] | ((unsigned int)o16[3] << 16);
  o.z = (unsigned int)o16[4] | ((unsigned int)o16[5] << 16);
  o.w = (unsigned int)o16[6] | ((unsigned int)o16[7] << 16);
  *(uint4*)&tout[(size_t)j * 512 + coff] = o;
}

// ---------------- GEMM: C[o][n] = sum_kc A[n][kc] * B[kc][o] + bias[o] ----------------
// 64n x 128o tile, 628 blocks (~2.5/CU TLP). Double-buffered LDS (48KB) +
// counted-vmcnt(6) pipeline + T2 XOR swizzle + bijective XCD chunking.
// Wave w computes n[0..64) x o[w*32..w*32+32): acc[4][2]. (round-16 exact)
__global__ __launch_bounds__(256) void gemm_kernel(
    const unsigned short* __restrict__ A,
    const unsigned short* __restrict__ Bt,
    const float* __restrict__ bias,
    float* __restrict__ C)
{
  __shared__ __align__(16) char smem[49152];          // 2 x (As 8KB + Bs 16KB); epi 34KB
  float* eps = (float*)smem;                          // epilogue [128 o][68 n] f32

  const int tid = threadIdx.x;
  const int wave = tid >> 6, lane = tid & 63;
  const int l15 = lane & 15, hi = lane >> 4;

  // bijective XCD-chunked mapping of 628 (n,o) pairs, n-major
  const int bid = blockIdx.x;                         // 0..631
  const int xcd = bid & 7, local = bid >> 3;
  const int qd = GM_PAIRS >> 3, rem = GM_PAIRS & 7;   // 78, 4
  const int cnt = (xcd < rem) ? qd + 1 : qd;
  if (local >= cnt) return;                           // whole block exits: safe
  const int start = (xcd < rem) ? xcd * (qd + 1) : rem * (qd + 1) + (xcd - rem) * qd;
  const int pair = start + local;
  const int n0 = (pair >> 2) * 64;                    // 0..9984 (overread in pad)
  const int o0 = (pair & 3) * 128;

  f32x4 acc[4][2];
#pragma unroll
  for (int a = 0; a < 4; ++a)
#pragma unroll
    for (int b = 0; b < 2; ++b) acc[a][b] = (f32x4){0.f, 0.f, 0.f, 0.f};

  // stage K-tile kt into buffer sel (6 gll16/thread: A 2, B 4).
  // LDS dest linear; global 16B-unit column pre-swizzled u_g = u ^ (r&7).
  auto stage = [&](int kt, int sel) {
    const int k0 = kt * 64;
    const int ko = k0 >> 9;
    const int c0 = k0 & 511;
    const unsigned short* Ab = A + (size_t)ko * ((size_t)N_NODES * 512);
    unsigned short* As = (unsigned short*)(smem + sel * 24576);
    unsigned short* Bs = As + 64 * 64;                // A 8KB, then B 16KB
#pragma unroll
    for (int q = 0; q < 2; ++q) {                     // A: 512 units
      int idx = (wave * 2 + q) * 64 + lane;
      int r = idx >> 3, u = idx & 7;
      int ug = u ^ (r & 7);
      gll16(Ab + (size_t)(n0 + r) * 512 + c0 + ug * 8, As + (size_t)(wave * 2 + q) * 512);
    }
#pragma unroll
    for (int q = 0; q < 4; ++q) {                     // B: 1024 units
      int idx = (wave * 4 + q) * 64 + lane;
      int r = idx >> 3, u = idx & 7;
      int ug = u ^ (r & 7);
      gll16(Bt + (size_t)(o0 + r) * 2560 + k0 + ug * 8, Bs + (size_t)(wave * 4 + q) * 512);
    }
  };

  stage(0, 0);
  asm volatile("s_waitcnt vmcnt(0)" ::: "memory");     // tile 0 resident
  __builtin_amdgcn_s_barrier();

  for (int kt = 0; kt < 40; ++kt) {
    const int cur = kt & 1;
    if (kt + 1 < 40) {
      stage(kt + 1, cur ^ 1);                          // 6 loads join flight
      asm volatile("s_waitcnt vmcnt(6)" ::: "memory"); // my tile-kt 6 complete
    } else {
      asm volatile("s_waitcnt vmcnt(0)" ::: "memory");
    }
    __builtin_amdgcn_s_barrier();                      // all waves: tile kt in LDS
    __builtin_amdgcn_sched_barrier(0);                 // pin ds_reads below
    unsigned short* As = (unsigned short*)(smem + cur * 24576);
    unsigned short* Bs = As + 64 * 64;
#pragma unroll
    for (int kk = 0; kk < 2; ++kk) {
      bf16x8 af[4], bfr[2];
#pragma unroll
      for (int mi = 0; mi < 4; ++mi) {
        int row = mi * 16 + l15;                       // 0..63
        int up = (kk * 4 + hi) ^ (row & 7);            // read-side XOR
        af[mi] = *(const bf16x8*)(As + row * 64 + up * 8);
      }
#pragma unroll
      for (int ni = 0; ni < 2; ++ni) {
        int row = wave * 32 + ni * 16 + l15;           // 0..127
        int up = (kk * 4 + hi) ^ (row & 7);
        bfr[ni] = *(const bf16x8*)(Bs + row * 64 + up * 8);
      }
#pragma unroll
      for (int mi = 0; mi < 4; ++mi)
#pragma unroll
        for (int ni = 0; ni < 2; ++ni)
          acc[mi][ni] = __builtin_amdgcn_mfma_f32_16x16x32_bf16(af[mi], bfr[ni], acc[mi][ni], 0, 0, 0);
    }
    __builtin_amdgcn_s_barrier();                      // reads done before overwrite
  }

  // epilogue: waves own disjoint o-ranges -> single pass
  __syncthreads();                                     // protect smem from K-loop reuse
#pragma unroll
  for (int mi = 0; mi < 4; ++mi)
#pragma unroll
    for (int ni = 0; ni < 2; ++ni) {
      int o_l = wave * 32 + ni * 16 + l15;             // 0..127
      int nb = mi * 16 + hi * 4;                       // 0..60
      *(f32x4*)&eps[o_l * 68 + nb] = acc[mi][ni];
    }
  __syncthreads();
#pragma unroll
  for (int q = 0; q < 8; ++q) {
    int unit = q * 256 + tid;                          // 2048 float4 units
    int o_l = unit >> 4, nu = unit & 15;
    int n = n0 + nu * 4;
    if (n < N_NODES) {
      int o = o0 + o_l;
      f32x4 v = *(const f32x4*)&eps[o_l * 68 + nu * 4];
      float bo = bias[o];
      v = v + bo;
      *(f32x4*)&C[(size_t)o * N_NODES + n] = v;
    }
  }
}

extern "C" void kernel_launch(void* const* d_in, const int* in_sizes, int n_in,
                              void* d_out, int out_size, void* d_ws, size_t ws_size,
                              hipStream_t stream)
{
  const float* x        = (const float*)d_in[0];   // [512][10000]
  const float* position = (const float*)d_in[1];   // [10000][3]
  const float* theta    = (const float*)d_in[2];   // [5][512][512]
  const float* bias     = (const float*)d_in[3];   // [512]

  char* ws = (char*)d_ws;
  size_t off = 0;
  auto alloc = [&](size_t bytes) -> void* {
    void* p = ws + off;
    off = (off + bytes + 255) & ~(size_t)255;
    return p;
  };
  unsigned short* TxAll   = (unsigned short*)alloc(5ull * N_NODES * 512 * 2 + 131072); // +128-row pad
  unsigned short* thetabT = (unsigned short*)alloc(512ull * 2560 * 2);
  float4* pos4  = (float4*)alloc((size_t)POS4_PAD * 16);
  float4* pos4s = (float4*)alloc((size_t)N_NODES * 16);
  int* knn    = (int*)alloc((size_t)NEDGE * 4);
  int* rptr   = (int*)alloc((size_t)(N_NODES + 1) * 4);
  int* counts = (int*)alloc((size_t)N_NODES * 4);
  int* cursor = (int*)alloc((size_t)N_NODES * 4);
  int* rsrc   = (int*)alloc((size_t)NEDGE * 4);
  int* cellcnt = (int*)alloc((size_t)NCELL * 4);   // contiguous with cellcur:
  int* cellcur = (int*)alloc((size_t)NCELL * 4);   // zeroed by theta-transpose
  int* cellptr = (int*)alloc((size_t)(NCELL + 1) * 4);
  int* cellid  = (int*)alloc((size_t)N_NODES * 4);
  int* perm    = (int*)alloc((size_t)N_NODES * 4);
  int* wl      = (int*)alloc((size_t)N_NODES * 4);
  int* nfail   = (int*)alloc(256);
  if (ws_size < off) return;   // insufficient scratch

  // theta [5][512][512] -> thetabT [o=512][kc=2560]; also zeroes cellcnt+cellcur
  transpose_f32_bf16<<<dim3(8, 8, 5), 256, 0, stream>>>(
      theta, thetabT, 512, 512, 2560, (size_t)512 * 512, 512, cellcnt);
  // x [512][10000] -> Tx0 [10000][512]
  transpose_f32_bf16<<<dim3(157, 8, 1), 256, 0, stream>>>(
      x, TxAll, 512, N_NODES, 512, 0, 0, nullptr);

  pos4_kernel<<<40, 256, 0, stream>>>(position, pos4, counts, cursor, cellid, cellcnt, nfail);
  cellscan_kernel<<<1, 256, 0, stream>>>(cellcnt, cellptr);
  perm_kernel<<<40, 256, 0, stream>>>(cellid, cellptr, cellcur, perm, pos4, pos4s);

  knn_try_kernel<<<2500, 256, 0, stream>>>(pos4, pos4s, perm, cellptr, knn, wl, nfail);
  knn_full_kernel<<<2500, 256, 0, stream>>>(pos4, wl, nfail, knn);

  count_kernel<<<(NEDGE + 255) / 256, 256, 0, stream>>>(knn, counts);
  scan_kernel<<<1, 256, 0, stream>>>(counts, rptr);
  fill_kernel<<<(NEDGE + 255) / 256, 256, 0, stream>>>(knn, rptr, cursor, rsrc);
  sort_kernel<<<2500, 256, 0, stream>>>(rptr, rsrc);

  unsigned short* Tx0 = TxAll;
  unsigned short* Tx1 = TxAll + 1ull * N_NODES * 512;
  unsigned short* Tx2 = TxAll + 2ull * N_NODES * 512;
  unsigned short* Tx3 = TxAll + 3ull * N_NODES * 512;
  unsigned short* Tx4 = TxAll + 4ull * N_NODES * 512;

  // Tx1 = prop(Tx0) = -0.05*sum ; Tx_k = 2*prop(Tx_{k-1}) - Tx_{k-2} = -0.10*sum - prev
  prop_kernel<<<2504, 256, 0, stream>>>(Tx0, nullptr, Tx1, rptr, rsrc, perm, -0.05f);
  prop_kernel<<<2504, 256, 0, stream>>>(Tx1, Tx0,     Tx2, rptr, rsrc, perm, -0.10f);
  prop_kernel<<<2504, 256, 0, stream>>>(Tx2, Tx1,     Tx3, rptr, rsrc, perm, -0.10f);
  prop_kernel<<<2504, 256, 0, stream>>>(Tx3, Tx2,     Tx4, rptr, rsrc, perm, -0.10f);

  gemm_kernel<<<632, 256, 0, stream>>>(TxAll, thetabT, bias, (float*)d_out);
}